// Round 4
// baseline (1455.176 us; speedup 1.0000x reference)
//
#include <hip/hip_runtime.h>

#define T_STEPS 512
#define NDIM    512
#define DDIM    64
#define BBATCH  256
#define BPB     4         // batches per scan block: per-CU VMEM stream = 16 KB/step
#define WLDS_STRIDE 136   // 128 k-halves + 8 pad (272B row: 16B-aligned, bank-spread)
#define XLDS_STRIDE 528   // 512 + 16 pad: 264 dwords == 8 mod 32 -> even x-read banks at BPB=4
#define XBUF (BPB * XLDS_STRIDE)
#define RF_OFF  0         // W_res reg-fragment region (halves) in tail
#define WI_OFF  196608    // W_in fragment region (halves) in tail

typedef _Float16 half8 __attribute__((ext_vector_type(8)));
typedef _Float16 half4 __attribute__((ext_vector_type(4)));
typedef float    f32x4 __attribute__((ext_vector_type(4)));

__device__ __forceinline__ float tanh_fast(float x) {
    // tanh(x) = 1 - 2/(e^{2x}+1). exp2->inf => rcp->0 => +1; exp2->0 => -1.
    float e = __builtin_amdgcn_exp2f(x * 2.885390081777927f);   // e^(2x)
    return 1.f - 2.f * __builtin_amdgcn_rcpf(e + 1.f);
}

// ---------------------------------------------------------------------------
// prep: gather fp16 MFMA fragments of W_res (k-tiles 4..15) and W_in into the
// d_out tail (final-state region; overwritten with real output at t=511).
// Fragment data for lane L: value[j] = W[k0 + (L>>4)*8 + j][ntg*16 + (L&15)].
// ---------------------------------------------------------------------------
__global__ void prep_kernel(const float* __restrict__ W_in,
                            const float* __restrict__ W_res,
                            _Float16* __restrict__ tail) {
    int id0 = blockIdx.x * blockDim.x + threadIdx.x;
    int stride = gridDim.x * blockDim.x;
    for (int id = id0; id < 12 * 32 * 64; id += stride) {       // W_res frags
        int ktr = id >> 11, rem = id & 2047;
        int ctg = rem >> 6, lane = rem & 63;
        int q = lane >> 4, c = lane & 15;
        int k0 = (ktr + 4) * 32 + q * 8;
        int n  = ctg * 16 + c;
        half8 v;
        #pragma unroll
        for (int j = 0; j < 8; ++j) v[j] = (_Float16)W_res[(size_t)(k0 + j) * NDIM + n];
        *(half8*)(tail + RF_OFF + (size_t)id * 8) = v;
    }
    for (int id = id0; id < 2 * 32 * 64; id += stride) {        // W_in frags
        int idx = id >> 6, lane = id & 63;
        int ktu = idx >> 5, ntg = idx & 31;
        int q = lane >> 4, c = lane & 15;
        int k0 = ktu * 32 + q * 8;
        int n  = ntg * 16 + c;
        half8 v;
        #pragma unroll
        for (int j = 0; j < 8; ++j) v[j] = (_Float16)W_in[(size_t)(k0 + j) * NDIM + n];
        *(half8*)(tail + WI_OFF + (size_t)id * 8) = v;
    }
}

// ---------------------------------------------------------------------------
// u_kernel: U = inputs @ W_in + b_in (+ b_res for all rows with t != 0),
// written into the X region of d_out.
// ---------------------------------------------------------------------------
__global__ __launch_bounds__(256) void u_kernel(const float* __restrict__ inputs,
                                                const float* __restrict__ b_in,
                                                const float* __restrict__ b_res,
                                                const _Float16* __restrict__ tail,
                                                float* __restrict__ U) {
    __shared__ _Float16 in_s[64 * 72];
    int tid = threadIdx.x;
    int w = tid >> 6, lane = tid & 63, q = lane >> 4, c = lane & 15;
    int row_base = blockIdx.x * 64;

    for (int i = tid; i < 1024; i += 256) {                     // stage 64x64 fp32 -> fp16
        f32x4 v = *(const f32x4*)(inputs + (size_t)row_base * DDIM + (size_t)i * 4);
        int row = i >> 4, d4 = (i & 15) * 4;
        half4 h; h[0]=(_Float16)v[0]; h[1]=(_Float16)v[1]; h[2]=(_Float16)v[2]; h[3]=(_Float16)v[3];
        *(half4*)(in_s + row * 72 + d4) = h;
    }
    __syncthreads();

    half8 a0 = *(const half8*)(in_s + (w * 16 + c) * 72 + q * 8);
    half8 a1 = *(const half8*)(in_s + (w * 16 + c) * 72 + 32 + q * 8);
    int row = row_base + w * 16 + q * 4;
    #pragma unroll 4
    for (int ntg = 0; ntg < 32; ++ntg) {
        int n = ntg * 16 + c;
        half8 b0 = *(const half8*)(tail + WI_OFF + ((size_t)ntg * 64 + lane) * 8);
        half8 b1 = *(const half8*)(tail + WI_OFF + ((size_t)(32 + ntg) * 64 + lane) * 8);
        float bv  = b_in[n];
        float brv = b_res[n];
        f32x4 acc = {bv, bv, bv, bv};
        acc = __builtin_amdgcn_mfma_f32_16x16x32_f16(a0, b0, acc, 0, 0, 0);
        acc = __builtin_amdgcn_mfma_f32_16x16x32_f16(a1, b1, acc, 0, 0, 0);
        #pragma unroll
        for (int r = 0; r < 4; ++r) {
            float o = acc[r] + ((((row + r) & (T_STEPS - 1)) != 0) ? brv : 0.f);
            U[(size_t)(row + r) * NDIM + n] = o;
        }
    }
}

// ---------------------------------------------------------------------------
// scan: 64 persistent blocks (one CU each), 512 threads (8 waves).
// Round-4: (a) BPB 8->4 — per-CU global stream 32->16 KB/step (rounds 2->3
// showed per-CU VMEM is ~0.56-additive on the critical path); B-operand
// slots 4..15 carry duplicated batches (cb = c&3), lanes c>=4 masked off
// stores. (b) XLDS_STRIDE 528 (264 dwords == 8 mod 32): even 8-access/bank
// x-reads at BPB=4 (520's ==4 mod 32 piles 16 lanes on one bank group).
// (c) x_lds double-buffered, ONE __syncthreads()/step: read buf[t&1], write
// buf[(t+1)&1] — WAR race gone by construction; keeps one vmcnt drain/step
// for wave phase-lock (round 1 proved removing drains entirely regresses).
// Kept: W_res k-tiles 0..3 in LDS / 4..15 in regs, xprev-in-registers,
// b_res folded into U, clamp-free tanh.
// ---------------------------------------------------------------------------
__global__ __launch_bounds__(512, 2) void scan_kernel(
        const float* __restrict__ W_res,
        const _Float16* __restrict__ tail, float* __restrict__ out) {
    __shared__ _Float16 W_lds[NDIM * WLDS_STRIDE];   // [ncol][k'] k' in [0,128)
    __shared__ _Float16 x_lds[2 * XBUF];             // 2 x [batch][k=ncol] fp16 state

    int tid = threadIdx.x;
    int w = tid >> 6, lane = tid & 63, q = lane >> 4, c = lane & 15;
    int b0 = blockIdx.x * BPB;
    int cb = c & (BPB - 1);             // batch sub-index (lanes c>=4 mirror c&3)
    bool act = (c < BPB);               // only these lanes own real output

    for (int idx = tid; idx < 128 * NDIM; idx += 512) {          // W_res k<128 -> LDS
        int k = idx >> 9, n = idx & 511;
        W_lds[n * WLDS_STRIDE + k] = (_Float16)W_res[idx];
    }
    for (int i = tid; i < 2 * XBUF; i += 512) x_lds[i] = (_Float16)0.f;

    half8 wreg[12][4];                                           // W_res k-tiles 4..15
    #pragma unroll
    for (int ktr = 0; ktr < 12; ++ktr)
        #pragma unroll
        for (int mt = 0; mt < 4; ++mt)
            wreg[ktr][mt] = *(const half8*)(tail + RF_OFF +
                ((size_t)(ktr * 32 + (w * 4 + mt)) * 64 + lane) * 8);

    int batch = b0 + cb;                // valid for ALL lanes (duplicated c>=4)
    int nbase = w * 64 + q * 4;         // + mt*16 + r = global n-col
    size_t outb = (size_t)batch * T_STEPS * NDIM;

    f32x4 Upre[4];
    #pragma unroll
    for (int mt = 0; mt < 4; ++mt)
        Upre[mt] = *(const f32x4*)(out + outb + nbase + mt * 16);   // U[b][0][*]

    half4 xprev[4];                     // this lane's own x state (fp16-rounded)
    #pragma unroll
    for (int mt = 0; mt < 4; ++mt)
        #pragma unroll
        for (int r = 0; r < 4; ++r) xprev[mt][r] = (_Float16)0.f;

    __syncthreads();

    for (int t = 0; t < T_STEPS; ++t) {
        const _Float16* xr = x_lds + (t & 1) * XBUF;             // state read buffer
        _Float16*       xw = x_lds + ((t + 1) & 1) * XBUF;       // state write buffer
        f32x4 acc[4];
        #pragma unroll
        for (int mt = 0; mt < 4; ++mt) acc[mt] = Upre[mt];       // b_res pre-folded
        if (t < T_STEPS - 1) {                                   // prefetch U[t+1]
            #pragma unroll
            for (int mt = 0; mt < 4; ++mt)
                Upre[mt] = *(const f32x4*)(out + outb + (size_t)(t + 1) * NDIM + nbase + mt * 16);
        }
        #pragma unroll
        for (int kt = 0; kt < 4; ++kt) {                         // LDS-resident k-tiles
            half8 xb = *(const half8*)(xr + cb * XLDS_STRIDE + kt * 32 + q * 8);
            #pragma unroll
            for (int mt = 0; mt < 4; ++mt) {
                half8 a = *(const half8*)(W_lds +
                    (size_t)((w * 4 + mt) * 16 + c) * WLDS_STRIDE + kt * 32 + q * 8);
                acc[mt] = __builtin_amdgcn_mfma_f32_16x16x32_f16(a, xb, acc[mt], 0, 0, 0);
            }
        }
        #pragma unroll
        for (int ktr = 0; ktr < 12; ++ktr) {                     // register k-tiles
            half8 xb = *(const half8*)(xr + cb * XLDS_STRIDE + (ktr + 4) * 32 + q * 8);
            #pragma unroll
            for (int mt = 0; mt < 4; ++mt)
                acc[mt] = __builtin_amdgcn_mfma_f32_16x16x32_f16(wreg[ktr][mt], xb, acc[mt], 0, 0, 0);
        }
        // epilogue: blend + tanh; store X (active lanes only); publish to xw
        #pragma unroll
        for (int mt = 0; mt < 4; ++mt) {
            f32x4 xn;
            #pragma unroll
            for (int r = 0; r < 4; ++r)
                xn[r] = 0.5f * ((float)xprev[mt][r] + tanh_fast(acc[mt][r]));
            if (act) {
                *(f32x4*)(out + outb + (size_t)t * NDIM + nbase + mt * 16) = xn;
                if (t == T_STEPS - 1)
                    *(f32x4*)(out + (size_t)BBATCH * T_STEPS * NDIM +
                              (size_t)batch * NDIM + nbase + mt * 16) = xn;
            }
            #pragma unroll
            for (int r = 0; r < 4; ++r) xprev[mt][r] = (_Float16)xn[r];
        }
        if (act) {
            #pragma unroll
            for (int mt = 0; mt < 4; ++mt)
                *(half4*)(xw + cb * XLDS_STRIDE + nbase + mt * 16) = xprev[mt];
        }
        __syncthreads();                                          // xw published
    }
}

extern "C" void kernel_launch(void* const* d_in, const int* in_sizes, int n_in,
                              void* d_out, int out_size, void* d_ws, size_t ws_size,
                              hipStream_t stream) {
    const float* inputs = (const float*)d_in[0];
    const float* W_in   = (const float*)d_in[1];
    const float* b_in   = (const float*)d_in[2];
    const float* W_res  = (const float*)d_in[3];
    const float* b_res  = (const float*)d_in[4];
    float* out = (float*)d_out;
    // fragment scratch lives in the final-state tail of d_out (rewritten at t=511)
    _Float16* tail = (_Float16*)(out + (size_t)BBATCH * T_STEPS * NDIM);

    prep_kernel<<<96, 256, 0, stream>>>(W_in, W_res, tail);
    u_kernel<<<(BBATCH * T_STEPS) / 64, 256, 0, stream>>>(inputs, b_in, b_res, tail, out);
    scan_kernel<<<BBATCH / BPB, 512, 0, stream>>>(W_res, tail, out);
}

// Round 6
// 1211.656 us; speedup vs baseline: 1.2010x; 1.2010x over previous
//
#include <hip/hip_runtime.h>

#define T_STEPS 512
#define NDIM    512
#define DDIM    64
#define BBATCH  256
#define BPB     4         // batches per scan block; n-slots 4-way duplicated
#define XLDS_STRIDE 528   // 512 + 16 pad: 264 dwords == 8 mod 32 -> even x-read banks
#define XBUF (BPB * XLDS_STRIDE)
#define RF_OFF  0         // W_res reg-fragment region (halves) in tail
#define WI_OFF  196608    // W_in fragment region (halves) in tail

typedef _Float16 half8 __attribute__((ext_vector_type(8)));
typedef _Float16 half4 __attribute__((ext_vector_type(4)));
typedef float    f32x4 __attribute__((ext_vector_type(4)));

__device__ __forceinline__ float tanh_fast(float x) {
    // tanh(x) = 1 - 2/(e^{2x}+1). exp2->inf => rcp->0 => +1; exp2->0 => -1.
    float e = __builtin_amdgcn_exp2f(x * 2.885390081777927f);   // e^(2x)
    return 1.f - 2.f * __builtin_amdgcn_rcpf(e + 1.f);
}

// ---------------------------------------------------------------------------
// prep: gather fp16 MFMA fragments of W_res (k-tiles 4..15) and W_in into the
// d_out tail (final-state region; overwritten with real output at t=511).
// Fragment data for lane L: value[j] = W[k0 + (L>>4)*8 + j][ntg*16 + (L&15)].
// ---------------------------------------------------------------------------
__global__ void prep_kernel(const float* __restrict__ W_in,
                            const float* __restrict__ W_res,
                            _Float16* __restrict__ tail) {
    int id0 = blockIdx.x * blockDim.x + threadIdx.x;
    int stride = gridDim.x * blockDim.x;
    for (int id = id0; id < 12 * 32 * 64; id += stride) {       // W_res frags
        int ktr = id >> 11, rem = id & 2047;
        int ctg = rem >> 6, lane = rem & 63;
        int q = lane >> 4, c = lane & 15;
        int k0 = (ktr + 4) * 32 + q * 8;
        int n  = ctg * 16 + c;
        half8 v;
        #pragma unroll
        for (int j = 0; j < 8; ++j) v[j] = (_Float16)W_res[(size_t)(k0 + j) * NDIM + n];
        *(half8*)(tail + RF_OFF + (size_t)id * 8) = v;
    }
    for (int id = id0; id < 2 * 32 * 64; id += stride) {        // W_in frags
        int idx = id >> 6, lane = id & 63;
        int ktu = idx >> 5, ntg = idx & 31;
        int q = lane >> 4, c = lane & 15;
        int k0 = ktu * 32 + q * 8;
        int n  = ntg * 16 + c;
        half8 v;
        #pragma unroll
        for (int j = 0; j < 8; ++j) v[j] = (_Float16)W_in[(size_t)(k0 + j) * NDIM + n];
        *(half8*)(tail + WI_OFF + (size_t)id * 8) = v;
    }
}

// ---------------------------------------------------------------------------
// u_kernel: U = inputs @ W_in + b_in (+ b_res for all rows with t != 0),
// written into the X region of d_out.
// ---------------------------------------------------------------------------
__global__ __launch_bounds__(256) void u_kernel(const float* __restrict__ inputs,
                                                const float* __restrict__ b_in,
                                                const float* __restrict__ b_res,
                                                const _Float16* __restrict__ tail,
                                                float* __restrict__ U) {
    __shared__ _Float16 in_s[64 * 72];
    int tid = threadIdx.x;
    int w = tid >> 6, lane = tid & 63, q = lane >> 4, c = lane & 15;
    int row_base = blockIdx.x * 64;

    for (int i = tid; i < 1024; i += 256) {                     // stage 64x64 fp32 -> fp16
        f32x4 v = *(const f32x4*)(inputs + (size_t)row_base * DDIM + (size_t)i * 4);
        int row = i >> 4, d4 = (i & 15) * 4;
        half4 h; h[0]=(_Float16)v[0]; h[1]=(_Float16)v[1]; h[2]=(_Float16)v[2]; h[3]=(_Float16)v[3];
        *(half4*)(in_s + row * 72 + d4) = h;
    }
    __syncthreads();

    half8 a0 = *(const half8*)(in_s + (w * 16 + c) * 72 + q * 8);
    half8 a1 = *(const half8*)(in_s + (w * 16 + c) * 72 + 32 + q * 8);
    int row = row_base + w * 16 + q * 4;
    #pragma unroll 4
    for (int ntg = 0; ntg < 32; ++ntg) {
        int n = ntg * 16 + c;
        half8 b0 = *(const half8*)(tail + WI_OFF + ((size_t)ntg * 64 + lane) * 8);
        half8 b1 = *(const half8*)(tail + WI_OFF + ((size_t)(32 + ntg) * 64 + lane) * 8);
        float bv  = b_in[n];
        float brv = b_res[n];
        f32x4 acc = {bv, bv, bv, bv};
        acc = __builtin_amdgcn_mfma_f32_16x16x32_f16(a0, b0, acc, 0, 0, 0);
        acc = __builtin_amdgcn_mfma_f32_16x16x32_f16(a1, b1, acc, 0, 0, 0);
        #pragma unroll
        for (int r = 0; r < 4; ++r) {
            float o = acc[r] + ((((row + r) & (T_STEPS - 1)) != 0) ? brv : 0.f);
            U[(size_t)(row + r) * NDIM + n] = o;
        }
    }
}

// ---------------------------------------------------------------------------
// scan: 64 persistent blocks (one CU each), 512 threads (8 waves), BPB=4.
// Round-6 = round-5 resubmit (container infra failure, kernel re-audited):
// (a) W_lds k-tiles 0..3 stored in MFMA-FRAGMENT-LINEAR layout (same format
//     as the register tiles in `tail`), staged in-kernel from W_res.
//     Wave reads become base + lane*16 — contiguous 1024B, ZERO bank
//     conflicts (was: 272B-row-stride reads, ~520 conflict-cyc/step/CU).
// (b) Epilogue redistributed across the 4 duplicate c-groups: group g=c>>2
//     finalizes only acc[g] (4 tanh/lane instead of 16; all 64 lanes store
//     one dwordx4). Duplicated B-slots make acc[g] identical across the
//     group, so this is exact. acc[g] selected via cndmask tree (rule #20).
// Kept: double-buffered x_lds + one __syncthreads()/step, W k-tiles 4..15
// in regs, b_res folded into U, clamp-free tanh.
// ---------------------------------------------------------------------------
__global__ __launch_bounds__(512, 2) void scan_kernel(
        const float* __restrict__ W_res,
        const _Float16* __restrict__ tail, float* __restrict__ out) {
    __shared__ _Float16 W_lds[4 * 32 * 64 * 8];      // k-tiles 0..3, fragment-linear (128 KB)
    __shared__ _Float16 x_lds[2 * XBUF];             // 2 x [batch][k=ncol] fp16 state

    int tid = threadIdx.x;
    int w = tid >> 6, lane = tid & 63, q = lane >> 4, c = lane & 15;
    int b0 = blockIdx.x * BPB;
    int cb = c & (BPB - 1);             // batch sub-index (lanes c>=4 mirror c&3)
    int g  = c >> 2;                    // duplicate-group: finalizes m-tile g

    // stage W_res k<128 as MFMA fragments (block (kt,ctg): lane L, elem j =
    // W_res[kt*32 + (L>>4)*8 + j][ctg*16 + (L&15)]), linear in LDS.
    for (int id = tid; id < 4 * 32 * 64; id += 512) {
        int kt = id >> 11, rem = id & 2047;
        int ctg = rem >> 6, L = rem & 63;
        int k0 = kt * 32 + (L >> 4) * 8;
        int n  = ctg * 16 + (L & 15);
        half8 v;
        #pragma unroll
        for (int j = 0; j < 8; ++j) v[j] = (_Float16)W_res[(size_t)(k0 + j) * NDIM + n];
        *(half8*)(W_lds + (size_t)id * 8) = v;
    }
    for (int i = tid; i < 2 * XBUF; i += 512) x_lds[i] = (_Float16)0.f;

    half8 wreg[12][4];                                           // W_res k-tiles 4..15
    #pragma unroll
    for (int ktr = 0; ktr < 12; ++ktr)
        #pragma unroll
        for (int mt = 0; mt < 4; ++mt)
            wreg[ktr][mt] = *(const half8*)(tail + RF_OFF +
                ((size_t)(ktr * 32 + (w * 4 + mt)) * 64 + lane) * 8);

    int batch = b0 + cb;                // valid for ALL lanes (duplicated c>=4)
    int nbase = w * 64 + q * 4;         // + mt*16 + r = global n-col (acc view)
    int colb  = w * 64 + g * 16 + q * 4; // 4 cols this lane finalizes (epilogue view)
    size_t outb = (size_t)batch * T_STEPS * NDIM;

    f32x4 Upre[4];
    #pragma unroll
    for (int mt = 0; mt < 4; ++mt)
        Upre[mt] = *(const f32x4*)(out + outb + nbase + mt * 16);   // U[b][0][*]

    half4 xprev;                        // x state for (batch, colb..colb+3)
    #pragma unroll
    for (int r = 0; r < 4; ++r) xprev[r] = (_Float16)0.f;

    bool g1 = (c & 4) != 0, g2 = (c & 8) != 0;

    __syncthreads();

    for (int t = 0; t < T_STEPS; ++t) {
        const _Float16* xr = x_lds + (t & 1) * XBUF;             // state read buffer
        _Float16*       xw = x_lds + ((t + 1) & 1) * XBUF;       // state write buffer
        f32x4 acc[4];
        #pragma unroll
        for (int mt = 0; mt < 4; ++mt) acc[mt] = Upre[mt];       // b_res pre-folded
        if (t < T_STEPS - 1) {                                   // prefetch U[t+1]
            #pragma unroll
            for (int mt = 0; mt < 4; ++mt)
                Upre[mt] = *(const f32x4*)(out + outb + (size_t)(t + 1) * NDIM + nbase + mt * 16);
        }
        #pragma unroll
        for (int kt = 0; kt < 4; ++kt) {                         // LDS-resident k-tiles
            half8 xb = *(const half8*)(xr + cb * XLDS_STRIDE + kt * 32 + q * 8);
            #pragma unroll
            for (int mt = 0; mt < 4; ++mt) {
                half8 a = *(const half8*)(W_lds +
                    ((size_t)((kt * 32 + (w * 4 + mt)) * 64 + lane)) * 8);
                acc[mt] = __builtin_amdgcn_mfma_f32_16x16x32_f16(a, xb, acc[mt], 0, 0, 0);
            }
        }
        #pragma unroll
        for (int ktr = 0; ktr < 12; ++ktr) {                     // register k-tiles
            half8 xb = *(const half8*)(xr + cb * XLDS_STRIDE + (ktr + 4) * 32 + q * 8);
            #pragma unroll
            for (int mt = 0; mt < 4; ++mt)
                acc[mt] = __builtin_amdgcn_mfma_f32_16x16x32_f16(wreg[ktr][mt], xb, acc[mt], 0, 0, 0);
        }
        // epilogue (redistributed): lane finalizes acc[g] only — 4 tanh/lane.
        f32x4 accg;
        #pragma unroll
        for (int r = 0; r < 4; ++r) {
            float lo = g1 ? acc[1][r] : acc[0][r];
            float hi = g1 ? acc[3][r] : acc[2][r];
            accg[r] = g2 ? hi : lo;
        }
        f32x4 xn;
        #pragma unroll
        for (int r = 0; r < 4; ++r)
            xn[r] = 0.5f * ((float)xprev[r] + tanh_fast(accg[r]));
        *(f32x4*)(out + outb + (size_t)t * NDIM + colb) = xn;
        if (t == T_STEPS - 1)
            *(f32x4*)(out + (size_t)BBATCH * T_STEPS * NDIM +
                      (size_t)batch * NDIM + colb) = xn;
        #pragma unroll
        for (int r = 0; r < 4; ++r) xprev[r] = (_Float16)xn[r];
        *(half4*)(xw + cb * XLDS_STRIDE + colb) = xprev;          // publish to other buf
        __syncthreads();                                          // xw published
    }
}

extern "C" void kernel_launch(void* const* d_in, const int* in_sizes, int n_in,
                              void* d_out, int out_size, void* d_ws, size_t ws_size,
                              hipStream_t stream) {
    const float* inputs = (const float*)d_in[0];
    const float* W_in   = (const float*)d_in[1];
    const float* b_in   = (const float*)d_in[2];
    const float* W_res  = (const float*)d_in[3];
    const float* b_res  = (const float*)d_in[4];
    float* out = (float*)d_out;
    // fragment scratch lives in the final-state tail of d_out (rewritten at t=511)
    _Float16* tail = (_Float16*)(out + (size_t)BBATCH * T_STEPS * NDIM);

    prep_kernel<<<96, 256, 0, stream>>>(W_in, W_res, tail);
    u_kernel<<<(BBATCH * T_STEPS) / 64, 256, 0, stream>>>(inputs, b_in, b_res, tail, out);
    scan_kernel<<<BBATCH / BPB, 512, 0, stream>>>(W_res, tail, out);
}